// Round 4
// baseline (44475.601 us; speedup 1.0000x reference)
//
#include <hip/hip_runtime.h>
#include <hip/hip_bf16.h>
#include <stdint.h>

#define SEQ   512
#define BATCH 128
#define DIM   1024
#define BD    (BATCH * DIM)   // 131072
#define WELEM (4 * DIM * DIM) // 4194304 elements per weight matrix

typedef __bf16 bf16x8 __attribute__((ext_vector_type(8)));
typedef float  f32x4  __attribute__((ext_vector_type(4)));

__device__ __forceinline__ bf16x8 ld_bf8(const __hip_bfloat16* p) {
    uint4 u = *reinterpret_cast<const uint4*>(p);
    return __builtin_bit_cast(bf16x8, u);
}

// Load 8 consecutive f32 and round to a bf16x8 fragment chunk.
__device__ __forceinline__ bf16x8 ld_f32_bf8(const float* p) {
    float4 a = *reinterpret_cast<const float4*>(p);
    float4 b = *reinterpret_cast<const float4*>(p + 4);
    bf16x8 r;
    r[0] = (__bf16)a.x; r[1] = (__bf16)a.y; r[2] = (__bf16)a.z; r[3] = (__bf16)a.w;
    r[4] = (__bf16)b.x; r[5] = (__bf16)b.y; r[6] = (__bf16)b.z; r[7] = (__bf16)b.w;
    return r;
}

__device__ __forceinline__ float sigf(float x) { return 1.0f / (1.0f + __expf(-x)); }

// Convert an f32 weight matrix to bf16 (once per launch; ~50 MB traffic).
__global__ __launch_bounds__(256) void cvt_w(
    const float* __restrict__ src, __hip_bfloat16* __restrict__ dst)
{
    int i = (blockIdx.x * blockDim.x + threadIdx.x) * 4;
    float4 v = *reinterpret_cast<const float4*>(src + i);
    dst[i + 0] = __float2bfloat16(v.x);
    dst[i + 1] = __float2bfloat16(v.y);
    dst[i + 2] = __float2bfloat16(v.z);
    dst[i + 3] = __float2bfloat16(v.w);
}

// One LSTM cell step. gates = A1 @ Wih^T + A2 @ Whh^T + bih + bhh (i,f,g,o).
// c_new = sig(f)*c_in + sig(i)*tanh(g); h_new = sig(o)*tanh(c_new)
// pad rows (xrow[b]==0): h_out = fb_h, c_out = fb_c.
// h1cell_out (if non-null) receives UNMASKED h_new (input for layer-2 cell).
__global__ __launch_bounds__(256) void lstm_cell(
    const int* __restrict__ xrow,
    const float* __restrict__ embf,            // f32 embedding (gather==1)
    const __hip_bfloat16* __restrict__ a1,     // bf16 h1 (gather==0)
    const __hip_bfloat16* __restrict__ a2,     // bf16 recurrent state
    const __hip_bfloat16* __restrict__ Wih,    // bf16 (ws copy)
    const __hip_bfloat16* __restrict__ Whh,    // bf16 (ws copy)
    const float* __restrict__ bih,
    const float* __restrict__ bhh,
    const float* __restrict__ c_in,
    const float* __restrict__ fb_h,
    const float* __restrict__ fb_c,
    float* __restrict__ h_out,
    float* __restrict__ c_out,
    __hip_bfloat16* __restrict__ hbf_out,
    __hip_bfloat16* __restrict__ h1cell_out,
    int gather)
{
    const int tid  = threadIdx.x;
    const int wave = tid >> 6;
    const int lane = tid & 63;
    const int quad = lane >> 4;
    const int l16  = lane & 15;
    const int bx   = blockIdx.x;
    const int mh   = bx & 1;        // M half (batch rows 0..63 / 64..127)
    const int grp  = bx >> 1;       // hidden-unit group of 16
    const int j0   = grp * 16;
    const int mbase = mh * 64 + wave * 16;
    const int arow_idx = mbase + l16;   // A-frag: A[m=lane&15][k=quad*8+j]

    const float* arow1f = nullptr;
    const __hip_bfloat16* arow1b = nullptr;
    if (gather) {
        int idx = xrow[arow_idx];
        arow1f = embf + (size_t)idx * DIM;
    } else {
        arow1b = a1 + (size_t)arow_idx * DIM;
    }
    const __hip_bfloat16* arow2 = a2 + (size_t)arow_idx * DIM;

    // B-frag: B[n=lane&15][k=quad*8+j]; W row-major [4D,D] == W^T operand.
    const __hip_bfloat16* w1[4];
    const __hip_bfloat16* w2[4];
    #pragma unroll
    for (int g = 0; g < 4; ++g) {
        size_t n = (size_t)(g * DIM + j0 + l16);
        w1[g] = Wih + n * DIM;
        w2[g] = Whh + n * DIM;
    }

    f32x4 acc[4];
    #pragma unroll
    for (int g = 0; g < 4; ++g) acc[g] = (f32x4)(0.0f);

    const int koff = quad * 8;

    if (gather) {
        #pragma unroll 4
        for (int k = 0; k < DIM; k += 32) {
            bf16x8 a = ld_f32_bf8(arow1f + k + koff);
            #pragma unroll
            for (int g = 0; g < 4; ++g) {
                bf16x8 b = ld_bf8(w1[g] + k + koff);
                acc[g] = __builtin_amdgcn_mfma_f32_16x16x32_bf16(a, b, acc[g], 0, 0, 0);
            }
        }
    } else {
        #pragma unroll 4
        for (int k = 0; k < DIM; k += 32) {
            bf16x8 a = ld_bf8(arow1b + k + koff);
            #pragma unroll
            for (int g = 0; g < 4; ++g) {
                bf16x8 b = ld_bf8(w1[g] + k + koff);
                acc[g] = __builtin_amdgcn_mfma_f32_16x16x32_bf16(a, b, acc[g], 0, 0, 0);
            }
        }
    }
    #pragma unroll 4
    for (int k = 0; k < DIM; k += 32) {
        bf16x8 a = ld_bf8(arow2 + k + koff);
        #pragma unroll
        for (int g = 0; g < 4; ++g) {
            bf16x8 b = ld_bf8(w2[g] + k + koff);
            acc[g] = __builtin_amdgcn_mfma_f32_16x16x32_bf16(a, b, acc[g], 0, 0, 0);
        }
    }

    // Epilogue. C/D layout (verified m89): col = lane&15, row = quad*4 + reg.
    const int j = j0 + l16;
    float bias[4];
    #pragma unroll
    for (int g = 0; g < 4; ++g)
        bias[g] = bih[g * DIM + j] + bhh[g * DIM + j];

    #pragma unroll
    for (int r = 0; r < 4; ++r) {
        int brow = mbase + quad * 4 + r;
        size_t off = (size_t)brow * DIM + j;
        float gi = acc[0][r] + bias[0];
        float gf = acc[1][r] + bias[1];
        float gg = acc[2][r] + bias[2];
        float go = acc[3][r] + bias[3];
        float c_old = c_in[off];
        float cn = sigf(gf) * c_old + sigf(gi) * tanhf(gg);
        float hn = sigf(go) * tanhf(cn);
        if (h1cell_out) h1cell_out[off] = __float2bfloat16(hn);  // unmasked, feeds layer 2
        bool pad = (xrow[brow] == 0);
        float hw = pad ? fb_h[off] : hn;
        float cw = pad ? fb_c[off] : cn;
        h_out[off]   = hw;
        c_out[off]   = cw;
        hbf_out[off] = __float2bfloat16(hw);
    }
}

__global__ __launch_bounds__(256) void init_state(
    const float* __restrict__ h0, const float* __restrict__ c0,
    const float* __restrict__ h02, const float* __restrict__ c02,
    float* __restrict__ h, float* __restrict__ c,
    float* __restrict__ h2, float* __restrict__ c2,
    __hip_bfloat16* __restrict__ hbf, __hip_bfloat16* __restrict__ h2bf)
{
    int i = blockIdx.x * blockDim.x + threadIdx.x;  // over B*D
    int j = i & (DIM - 1);
    float hv = h0[j], h2v = h02[j];
    h[i]  = hv;
    c[i]  = c0[j];
    h2[i] = h2v;
    c2[i] = c02[j];
    hbf[i]  = __float2bfloat16(hv);
    h2bf[i] = __float2bfloat16(h2v);
}

// Output buffer is FLOAT32 (reference's declared output dtype).
__global__ __launch_bounds__(256) void pack_out(
    const float* __restrict__ h, const float* __restrict__ c,
    const float* __restrict__ h2, const float* __restrict__ c2,
    float* __restrict__ out)
{
    int i = blockIdx.x * blockDim.x + threadIdx.x;  // over 4*B*D
    int sec = i >> 17;          // BD = 2^17
    int off = i & (BD - 1);
    const float* src = (sec == 0) ? h : (sec == 1) ? c : (sec == 2) ? h2 : c2;
    out[i] = src[off];
}

extern "C" void kernel_launch(void* const* d_in, const int* in_sizes, int n_in,
                              void* d_out, int out_size, void* d_ws, size_t ws_size,
                              hipStream_t stream) {
    (void)in_sizes; (void)n_in; (void)out_size; (void)ws_size;
    const int*   x    = (const int*)d_in[0];
    const float* emb  = (const float*)d_in[1];
    const float* Wih  = (const float*)d_in[2];
    const float* Whh  = (const float*)d_in[3];
    const float* bih  = (const float*)d_in[4];
    const float* bhh  = (const float*)d_in[5];
    const float* h0   = (const float*)d_in[6];
    const float* c0   = (const float*)d_in[7];
    const float* h02  = (const float*)d_in[8];
    const float* c02  = (const float*)d_in[9];

    // ws: 8 f32 state buffers (4 MB) + 5 bf16 shadows (1.25 MB) + bf16 W copies (16 MB).
    float* f = (float*)d_ws;
    float* hS[2]  = { f + 0 * BD, f + 1 * BD };
    float* cS[2]  = { f + 2 * BD, f + 3 * BD };
    float* h2S[2] = { f + 4 * BD, f + 5 * BD };
    float* c2S[2] = { f + 6 * BD, f + 7 * BD };
    __hip_bfloat16* bfb = (__hip_bfloat16*)(f + 8 * BD);
    __hip_bfloat16* hbf[2]  = { bfb + 0 * BD, bfb + 1 * BD };
    __hip_bfloat16* h2bf[2] = { bfb + 2 * BD, bfb + 3 * BD };
    __hip_bfloat16* h1cell  = bfb + 4 * BD;
    __hip_bfloat16* Wihb    = bfb + 5 * BD;
    __hip_bfloat16* Whhb    = Wihb + WELEM;

    cvt_w<<<WELEM / 1024, 256, 0, stream>>>(Wih, Wihb);
    cvt_w<<<WELEM / 1024, 256, 0, stream>>>(Whh, Whhb);

    init_state<<<BD / 256, 256, 0, stream>>>(h0, c0, h02, c02,
        hS[0], cS[0], h2S[0], c2S[0], hbf[0], h2bf[0]);

    for (int t = 0; t < SEQ; ++t) {
        int in = t & 1, out = in ^ 1;
        const int* xrow = x + t * BATCH;
        // layer 1: A1 = emb[x[t]] (f32 gather), A2 = h_bf
        lstm_cell<<<128, 256, 0, stream>>>(xrow, emb, nullptr, hbf[in],
            Wihb, Whhb, bih, bhh,
            cS[in], hS[in], cS[in],
            hS[out], cS[out], hbf[out], h1cell, 1);
        // layer 2: A1 = h1 (unmasked bf16), A2 = h2_bf; pad fallback = layer-1 PRE-state
        lstm_cell<<<128, 256, 0, stream>>>(xrow, emb, h1cell, h2bf[in],
            Wihb, Whhb, bih, bhh,
            c2S[in], hS[in], cS[in],
            h2S[out], c2S[out], h2bf[out], nullptr, 0);
    }
    // SEQ even -> final states land in parity-0 buffers.
    pack_out<<<(4 * BD) / 256, 256, 0, stream>>>(hS[0], cS[0], h2S[0], c2S[0],
        (float*)d_out);
}

// Round 5
// 41364.023 us; speedup vs baseline: 1.0752x; 1.0752x over previous
//
#include <hip/hip_runtime.h>
#include <hip/hip_bf16.h>
#include <stdint.h>

#define SEQ   512
#define BATCH 128
#define DIM   1024
#define BD    (BATCH * DIM)   // 131072
#define WELEM (4 * DIM * DIM) // 4194304 elements per weight matrix

typedef __bf16 bf16x8 __attribute__((ext_vector_type(8)));
typedef float  f32x4  __attribute__((ext_vector_type(4)));

__device__ __forceinline__ bf16x8 ld_bf8(const __hip_bfloat16* p) {
    uint4 u = *reinterpret_cast<const uint4*>(p);
    return __builtin_bit_cast(bf16x8, u);
}

// Load 8 consecutive f32 and round to a bf16x8 fragment chunk.
__device__ __forceinline__ bf16x8 ld_f32_bf8(const float* p) {
    float4 a = *reinterpret_cast<const float4*>(p);
    float4 b = *reinterpret_cast<const float4*>(p + 4);
    bf16x8 r;
    r[0] = (__bf16)a.x; r[1] = (__bf16)a.y; r[2] = (__bf16)a.z; r[3] = (__bf16)a.w;
    r[4] = (__bf16)b.x; r[5] = (__bf16)b.y; r[6] = (__bf16)b.z; r[7] = (__bf16)b.w;
    return r;
}

__device__ __forceinline__ float sigf(float x) { return 1.0f / (1.0f + __expf(-x)); }

// Convert an f32 weight matrix to bf16 (once per launch).
__global__ __launch_bounds__(256) void cvt_w(
    const float* __restrict__ src, __hip_bfloat16* __restrict__ dst)
{
    int i = (blockIdx.x * blockDim.x + threadIdx.x) * 4;
    float4 v = *reinterpret_cast<const float4*>(src + i);
    dst[i + 0] = __float2bfloat16(v.x);
    dst[i + 1] = __float2bfloat16(v.y);
    dst[i + 2] = __float2bfloat16(v.z);
    dst[i + 3] = __float2bfloat16(v.w);
}

__global__ __launch_bounds__(256) void bias_sum(
    const float* __restrict__ bih, const float* __restrict__ bhh,
    float* __restrict__ bsum)
{
    int i = blockIdx.x * blockDim.x + threadIdx.x;   // over 4*DIM
    bsum[i] = bih[i] + bhh[i];
}

// One LSTM cell step, 128 blocks x 512 threads.
// Block = (j-group of 16 hidden units [64], M-half [2]).
// Wave w = mt*2+s: mt = M-tile (16 rows of the 64-row half), s: 0 = A1@Wih^T, 1 = A2@Whh^T.
// Partials meet in LDS; thread-per-cell epilogue does bias+nonlinearity+pad-mask.
__global__ __launch_bounds__(512) void lstm_cell(
    const int* __restrict__ xrow,
    const float* __restrict__ embf,            // f32 embedding (gather==1)
    const __hip_bfloat16* __restrict__ a1b,    // bf16 A1 (gather==0: h1cell)
    const __hip_bfloat16* __restrict__ a2b,    // bf16 recurrent state
    const __hip_bfloat16* __restrict__ Wih,    // bf16 ws copy
    const __hip_bfloat16* __restrict__ Whh,    // bf16 ws copy
    const float* __restrict__ bsum,            // bih+bhh [4*DIM]
    const float* __restrict__ c_in,
    const float* __restrict__ fb_h,
    const float* __restrict__ fb_c,
    float* __restrict__ h_out,
    float* __restrict__ c_out,
    __hip_bfloat16* __restrict__ hbf_out,
    __hip_bfloat16* __restrict__ h1cell_out,   // non-null only for layer 1 (unmasked h)
    int gather)
{
    // part[w8][g4][row16][j17] f32, j-dim padded to 17
    __shared__ float part[8 * 4 * 16 * 17];

    const int tid  = threadIdx.x;
    const int wv   = tid >> 6;      // 0..7
    const int lane = tid & 63;
    const int quad = lane >> 4;
    const int l16  = lane & 15;
    const int mt   = wv >> 1;       // 0..3
    const int s    = wv & 1;        // matrix select
    const int bx   = blockIdx.x;
    const int grp  = bx >> 1;       // j-group 0..63
    const int mh   = bx & 1;        // M half
    const int j0   = grp * 16;
    const int mbase = mh * 64 + mt * 16;
    const int arow  = mbase + l16;  // A-frag: A[m=lane&15][k=quad*8+jj]
    const int koff  = quad * 8;

    const __hip_bfloat16* W = s ? Whh : Wih;
    const __hip_bfloat16* wrow[4];
    #pragma unroll
    for (int g = 0; g < 4; ++g)
        wrow[g] = W + (size_t)(g * DIM + j0 + l16) * DIM;   // B-frag: B[n=lane&15][k=quad*8+jj]

    f32x4 acc[4];
    #pragma unroll
    for (int g = 0; g < 4; ++g) acc[g] = (f32x4)(0.0f);

    if (s == 0 && gather) {
        const float* a = embf + (size_t)xrow[arow] * DIM;
        #pragma unroll 4
        for (int k = 0; k < DIM; k += 32) {
            bf16x8 af = ld_f32_bf8(a + k + koff);
            #pragma unroll
            for (int g = 0; g < 4; ++g) {
                bf16x8 b = ld_bf8(wrow[g] + k + koff);
                acc[g] = __builtin_amdgcn_mfma_f32_16x16x32_bf16(af, b, acc[g], 0, 0, 0);
            }
        }
    } else {
        const __hip_bfloat16* a = (s ? a2b : a1b) + (size_t)arow * DIM;
        #pragma unroll 4
        for (int k = 0; k < DIM; k += 32) {
            bf16x8 af = ld_bf8(a + k + koff);
            #pragma unroll
            for (int g = 0; g < 4; ++g) {
                bf16x8 b = ld_bf8(wrow[g] + k + koff);
                acc[g] = __builtin_amdgcn_mfma_f32_16x16x32_bf16(af, b, acc[g], 0, 0, 0);
            }
        }
    }

    // Store partials. C/D layout (m89): col = lane&15, row = quad*4 + reg.
    #pragma unroll
    for (int g = 0; g < 4; ++g)
        #pragma unroll
        for (int r = 0; r < 4; ++r)
            part[((wv * 4 + g) * 16 + quad * 4 + r) * 17 + l16] = acc[g][r];

    __syncthreads();

    // Epilogue: 512 threads x 2 cells; cell = (row in M-half, j).
    #pragma unroll
    for (int half = 0; half < 2; ++half) {
        int row = (tid >> 4) + half * 32;   // 0..63
        int j   = tid & 15;
        int mt2 = row >> 4, r16 = row & 15;
        float gate[4];
        #pragma unroll
        for (int g = 0; g < 4; ++g)
            gate[g] = part[(((mt2 * 2 + 0) * 4 + g) * 16 + r16) * 17 + j]
                    + part[(((mt2 * 2 + 1) * 4 + g) * 16 + r16) * 17 + j]
                    + bsum[g * DIM + j0 + j];
        int brow = mh * 64 + row;
        size_t off = (size_t)brow * DIM + j0 + j;
        float c_old = c_in[off];
        float cn = sigf(gate[1]) * c_old + sigf(gate[0]) * tanhf(gate[2]);
        float hn = sigf(gate[3]) * tanhf(cn);
        if (h1cell_out) h1cell_out[off] = __float2bfloat16(hn);  // unmasked, feeds layer 2
        bool pad = (xrow[brow] == 0);
        float hw = pad ? fb_h[off] : hn;
        float cw = pad ? fb_c[off] : cn;
        h_out[off]   = hw;
        c_out[off]   = cw;
        hbf_out[off] = __float2bfloat16(hw);
    }
}

__global__ __launch_bounds__(256) void init_state(
    const float* __restrict__ h0, const float* __restrict__ c0,
    const float* __restrict__ h02, const float* __restrict__ c02,
    float* __restrict__ h, float* __restrict__ c,
    float* __restrict__ h2, float* __restrict__ c2,
    __hip_bfloat16* __restrict__ hbf, __hip_bfloat16* __restrict__ h2bf)
{
    int i = blockIdx.x * blockDim.x + threadIdx.x;  // over B*D
    int j = i & (DIM - 1);
    float hv = h0[j], h2v = h02[j];
    h[i]  = hv;
    c[i]  = c0[j];
    h2[i] = h2v;
    c2[i] = c02[j];
    hbf[i]  = __float2bfloat16(hv);
    h2bf[i] = __float2bfloat16(h2v);
}

// Output buffer is FLOAT32 (reference's declared output dtype).
__global__ __launch_bounds__(256) void pack_out(
    const float* __restrict__ h, const float* __restrict__ c,
    const float* __restrict__ h2, const float* __restrict__ c2,
    float* __restrict__ out)
{
    int i = blockIdx.x * blockDim.x + threadIdx.x;  // over 4*B*D
    int sec = i >> 17;          // BD = 2^17
    int off = i & (BD - 1);
    const float* src = (sec == 0) ? h : (sec == 1) ? c : (sec == 2) ? h2 : c2;
    out[i] = src[off];
}

extern "C" void kernel_launch(void* const* d_in, const int* in_sizes, int n_in,
                              void* d_out, int out_size, void* d_ws, size_t ws_size,
                              hipStream_t stream) {
    (void)in_sizes; (void)n_in; (void)out_size; (void)ws_size;
    const int*   x    = (const int*)d_in[0];
    const float* emb  = (const float*)d_in[1];
    const float* Wih  = (const float*)d_in[2];
    const float* Whh  = (const float*)d_in[3];
    const float* bih  = (const float*)d_in[4];
    const float* bhh  = (const float*)d_in[5];
    const float* h0   = (const float*)d_in[6];
    const float* c0   = (const float*)d_in[7];
    const float* h02  = (const float*)d_in[8];
    const float* c02  = (const float*)d_in[9];

    // ws: 8 f32 state buffers + bsum + bf16 shadows + bf16 W copies (~22 MB).
    float* f = (float*)d_ws;
    float* hS[2]  = { f + 0 * BD, f + 1 * BD };
    float* cS[2]  = { f + 2 * BD, f + 3 * BD };
    float* h2S[2] = { f + 4 * BD, f + 5 * BD };
    float* c2S[2] = { f + 6 * BD, f + 7 * BD };
    float* bsum   = f + 8 * BD;                      // 4*DIM floats
    __hip_bfloat16* bfb = (__hip_bfloat16*)(bsum + 4 * DIM);
    __hip_bfloat16* hbf[2]  = { bfb + 0 * BD, bfb + 1 * BD };
    __hip_bfloat16* h2bf[2] = { bfb + 2 * BD, bfb + 3 * BD };
    __hip_bfloat16* h1cell  = bfb + 4 * BD;
    __hip_bfloat16* Wihb    = bfb + 5 * BD;
    __hip_bfloat16* Whhb    = Wihb + WELEM;

    cvt_w<<<WELEM / 1024, 256, 0, stream>>>(Wih, Wihb);
    cvt_w<<<WELEM / 1024, 256, 0, stream>>>(Whh, Whhb);
    bias_sum<<<(4 * DIM) / 256, 256, 0, stream>>>(bih, bhh, bsum);

    init_state<<<BD / 256, 256, 0, stream>>>(h0, c0, h02, c02,
        hS[0], cS[0], h2S[0], c2S[0], hbf[0], h2bf[0]);

    for (int t = 0; t < SEQ; ++t) {
        int in = t & 1, out = in ^ 1;
        const int* xrow = x + t * BATCH;
        // layer 1: A1 = emb[x[t]] (f32 gather), A2 = h_bf
        lstm_cell<<<128, 512, 0, stream>>>(xrow, emb, nullptr, hbf[in],
            Wihb, Whhb, bsum,
            cS[in], hS[in], cS[in],
            hS[out], cS[out], hbf[out], h1cell, 1);
        // layer 2: A1 = h1 (unmasked bf16), A2 = h2_bf; pad fallback = layer-1 PRE-state
        lstm_cell<<<128, 512, 0, stream>>>(xrow, emb, h1cell, h2bf[in],
            Wihb, Whhb, bsum,
            c2S[in], hS[in], cS[in],
            h2S[out], c2S[out], h2bf[out], nullptr, 0);
    }
    // SEQ even -> final states land in parity-0 buffers.
    pack_out<<<(4 * BD) / 256, 256, 0, stream>>>(hS[0], cS[0], h2S[0], c2S[0],
        (float*)d_out);
}